// Round 1
// baseline (113.044 us; speedup 1.0000x reference)
//
#include <hip/hip_runtime.h>

// Problem constants
#define V 8
#define B 32
#define CIN 8
#define T 4096
#define O 64
#define K 5
#define H 16

// Padded xs row: [0..3]=0, data at [4..4099], [4100..4103]=0.
// conv(t) = sum_j w[j]*xs[t+j-2] = sum_j w[j]*xs_pad[t+j+2]
#define XSTRIDE 4104

// workspace layout (floats)
#define XS_OFF 0
#define S_OFF  (V*B*XSTRIDE)          // 1050624
#define AF_OFF (S_OFF + V*B*O)        // +16384
#define AT_OFF (AF_OFF + V*B)         // +256
#define SM_OFF (AT_OFF + V*B)         // +256; size V*V*B = 2048

__device__ __forceinline__ float selu_f(float x) {
    const float SC = 1.0507009873554805f;
    const float SA = 1.7580993408473766f;  // scale*alpha
    float e = __expf(x);
    float neg = SA * e - SA;               // scale*alpha*(exp(x)-1)
    return x > 0.0f ? SC * x : neg;
}

// K0: xs[v,b,t] = sum_c x[v,b,c,t], written padded. grid=V*B, block=256
__global__ void k_xs(const float* __restrict__ x, float* __restrict__ ws) {
    int row = blockIdx.x;                  // v*B + b
    int tid = threadIdx.x;
    const float* xr = x + (size_t)row * CIN * T;
    float* xp = ws + XS_OFF + (size_t)row * XSTRIDE;
    for (int t = tid; t < T; t += 256) {
        float a = 0.0f;
        #pragma unroll
        for (int c = 0; c < CIN; ++c) a += xr[c * T + t];
        xp[t + 4] = a;
    }
    if (tid < 4) { xp[tid] = 0.0f; xp[4100 + tid] = 0.0f; }
}

// K1: s[v,b,o] = mean_t selu(conv). grid=V*B, block=512 (8 waves).
// lane = o (wave-uniform xs loads broadcast), wave = t-chunk of 512.
__global__ void k_mean(const float* __restrict__ ws, const float* __restrict__ cw,
                       const float* __restrict__ cb, float* __restrict__ s_out) {
    int row = blockIdx.x;
    int tid = threadIdx.x;
    int wave = tid >> 6;                   // 0..7
    int lane = tid & 63;                   // = o
    const float* xp = ws + XS_OFF + (size_t)row * XSTRIDE;
    float w0 = cw[lane * 5 + 0], w1 = cw[lane * 5 + 1], w2 = cw[lane * 5 + 2];
    float w3 = cw[lane * 5 + 3], w4 = cw[lane * 5 + 4];
    float bv = cb[lane];
    int c0 = wave * 512;
    float a0 = xp[c0 + 2], a1 = xp[c0 + 3], a2 = xp[c0 + 4], a3 = xp[c0 + 5];
    float acc = 0.0f;
    #pragma unroll 8
    for (int t = c0; t < c0 + 512; ++t) {
        float a4 = xp[t + 6];
        float cv = bv + w0 * a0 + w1 * a1 + w2 * a2 + w3 * a3 + w4 * a4;
        acc += selu_f(cv);
        a0 = a1; a1 = a2; a2 = a3; a3 = a4;
    }
    __shared__ float part[8][64];
    part[wave][lane] = acc;
    __syncthreads();
    if (tid < 64) {
        float tot = 0.0f;
        #pragma unroll
        for (int w = 0; w < 8; ++w) tot += part[w][tid];
        s_out[row * 64 + tid] = tot * (1.0f / (float)T);
    }
}

// K2: SE MLP -> gate -> compressed -> af/at dots. grid=V*B, block=64 (1 wave)
__global__ void k_se(const float* __restrict__ s_in, const float* __restrict__ w1,
                     const float* __restrict__ b1, const float* __restrict__ w2,
                     const float* __restrict__ b2, const float* __restrict__ awv,
                     float* __restrict__ af, float* __restrict__ at) {
    int blk = blockIdx.x;                  // v*32 + b
    int v = blk >> 5;
    int b = blk & 31;
    int o = threadIdx.x;                   // 0..63
    __shared__ float ssh[64];
    __shared__ float hsh[16];
    float so = s_in[blk * 64 + o];
    ssh[o] = so;
    __syncthreads();
    if (o < 16) {
        float hv = b1[v * 16 + o];
        #pragma unroll
        for (int j = 0; j < 64; ++j) hv += ssh[j] * w1[(v * 16 + o) * 64 + j];
        hsh[o] = fmaxf(hv, 0.0f);
    }
    __syncthreads();
    float gv = b2[v * 64 + o];
    #pragma unroll
    for (int j = 0; j < 16; ++j) gv += hsh[j] * w2[(v * 64 + o) * 16 + j];
    float gate = 1.0f / (1.0f + __expf(-gv));
    float comp = so * gate;
    float pf = comp * awv[o];
    float pt = comp * awv[64 + o];
    #pragma unroll
    for (int m = 32; m >= 1; m >>= 1) {
        pf += __shfl_xor(pf, m, 64);
        pt += __shfl_xor(pt, m, 64);
    }
    if (o == 0) { af[v * 32 + b] = pf; at[v * 32 + b] = pt; }
}

// K3: sm[f,g,b] = softmax_f selu(af[f,b]+at[g,b]). grid=B, block=64 (f=tid>>3,g=tid&7)
__global__ void k_sm(const float* __restrict__ af, const float* __restrict__ at,
                     float* __restrict__ sm) {
    int b = blockIdx.x;
    int tid = threadIdx.x;
    int f = tid >> 3, g = tid & 7;
    float a = selu_f(af[f * 32 + b] + at[g * 32 + b]);
    float m = a;
    m = fmaxf(m, __shfl_xor(m, 8, 64));
    m = fmaxf(m, __shfl_xor(m, 16, 64));
    m = fmaxf(m, __shfl_xor(m, 32, 64));
    float e = __expf(a - m);
    float ssum = e;
    ssum += __shfl_xor(ssum, 8, 64);
    ssum += __shfl_xor(ssum, 16, 64);
    ssum += __shfl_xor(ssum, 32, 64);
    sm[b * 64 + tid] = e / ssum;           // layout [b][f*8+g]
}

// K4: out[g,b,o,t] = sum_f sm[f,g,b]*selu(conv[f,b,o,t]), conv recomputed.
// grid = B * (T/256) * 4 o-groups = 2048 blocks, block=256. thread owns (b, t), 16 o's.
__global__ void k_out(const float* __restrict__ ws, const float* __restrict__ cw,
                      const float* __restrict__ cb, float* __restrict__ out) {
    int blk = blockIdx.x;
    int b = blk >> 6;                      // 0..31
    int r = blk & 63;
    int tile = r >> 2;                     // 0..15
    int og = r & 3;                        // 0..3
    int t = tile * 256 + threadIdx.x;

    const float* smp = ws + SM_OFF + b * 64;
    float smv[64];
    #pragma unroll
    for (int i = 0; i < 64; ++i) smv[i] = smp[i];   // [f*8+g], b uniform -> scalar

    float xw[8][5];
    #pragma unroll
    for (int f = 0; f < 8; ++f) {
        const float* xp = ws + XS_OFF + (size_t)(f * B + b) * XSTRIDE + t + 2;
        #pragma unroll
        for (int j = 0; j < 5; ++j) xw[f][j] = xp[j];
    }

    #pragma unroll 1
    for (int oi = 0; oi < 16; ++oi) {
        int o = og * 16 + oi;
        float w0 = cw[o * 5 + 0], w1 = cw[o * 5 + 1], w2 = cw[o * 5 + 2];
        float w3 = cw[o * 5 + 3], w4 = cw[o * 5 + 4];
        float bv = cb[o];
        float cf[8];
        #pragma unroll
        for (int f = 0; f < 8; ++f) {
            float cv = bv + w0 * xw[f][0] + w1 * xw[f][1] + w2 * xw[f][2]
                          + w3 * xw[f][3] + w4 * xw[f][4];
            cf[f] = selu_f(cv);
        }
        #pragma unroll
        for (int g = 0; g < 8; ++g) {
            float acc = 0.0f;
            #pragma unroll
            for (int f = 0; f < 8; ++f) acc += smv[f * 8 + g] * cf[f];
            out[((size_t)(g * B + b) * O + o) * T + t] = acc;
        }
    }
}

extern "C" void kernel_launch(void* const* d_in, const int* in_sizes, int n_in,
                              void* d_out, int out_size, void* d_ws, size_t ws_size,
                              hipStream_t stream) {
    const float* x      = (const float*)d_in[0];
    const float* conv_w = (const float*)d_in[1];
    const float* conv_b = (const float*)d_in[2];
    const float* se_w1  = (const float*)d_in[3];
    const float* se_b1  = (const float*)d_in[4];
    const float* se_w2  = (const float*)d_in[5];
    const float* se_b2  = (const float*)d_in[6];
    const float* attn_w = (const float*)d_in[7];
    float* out = (float*)d_out;
    float* ws  = (float*)d_ws;

    k_xs<<<V * B, 256, 0, stream>>>(x, ws);
    k_mean<<<V * B, 512, 0, stream>>>(ws, conv_w, conv_b, ws + S_OFF);
    k_se<<<V * B, 64, 0, stream>>>(ws + S_OFF, se_w1, se_b1, se_w2, se_b2, attn_w,
                                   ws + AF_OFF, ws + AT_OFF);
    k_sm<<<B, 64, 0, stream>>>(ws + AF_OFF, ws + AT_OFF, ws + SM_OFF);
    k_out<<<B * (T / 256) * 4, 256, 0, stream>>>(ws, conv_w, conv_b, out);
}

// Round 2
// 107.359 us; speedup vs baseline: 1.0530x; 1.0530x over previous
//
#include <hip/hip_runtime.h>

// Problem constants
#define V 8
#define B 32
#define CIN 8
#define T 4096
#define O 64
#define K 5
#define H 16

// Padded xs row: [0..3]=0, data at [4..4099], [4100..4103]=0.
// conv(t) = sum_j w[j]*xs[t+j-2] = sum_j w[j]*xs_pad[t+j+2]
#define XSTRIDE 4104

// workspace layout (floats)
#define XS_OFF 0
#define S_OFF  (V*B*XSTRIDE)          // xs: 256 rows * 4104
#define SM_OFF (S_OFF + V*B*O)        // s means; sm follows
// sm size: B*64

__device__ __forceinline__ float selu_f(float x) {
    const float SC = 1.0507009873554805f;
    const float SA = 1.7580993408473766f;  // scale*alpha
    float e = __expf(x);
    float neg = SA * e - SA;               // scale*alpha*(exp(x)-1)
    return x > 0.0f ? SC * x : neg;
}

__device__ __forceinline__ float sload(const float* p) {
    // force block-uniform value into SGPR
    return __int_as_float(__builtin_amdgcn_readfirstlane(__float_as_int(*p)));
}

// K01: xs row build (LDS + global) + per-(row,o) mean of selu(conv).
// grid = V*B (=256), block = 512 (8 waves).
__global__ __launch_bounds__(512) void k_xs_mean(
        const float* __restrict__ x, const float* __restrict__ cw,
        const float* __restrict__ cb, float* __restrict__ ws,
        float* __restrict__ s_out) {
    int row = blockIdx.x;                  // v*B + b
    int tid = threadIdx.x;
    __shared__ float xsh[XSTRIDE];
    const float* xr = x + (size_t)row * CIN * T;
    float* xp = ws + XS_OFF + (size_t)row * XSTRIDE;

    // Phase 1: xs = sum_c x[..c..], 8 t's per thread, float4 I/O.
    {
        int t0 = tid * 8;
        float4 a0 = make_float4(0.f, 0.f, 0.f, 0.f);
        float4 a1 = make_float4(0.f, 0.f, 0.f, 0.f);
        #pragma unroll
        for (int c = 0; c < CIN; ++c) {
            const float4* q = (const float4*)(xr + c * T + t0);
            float4 u = q[0], v2 = q[1];
            a0.x += u.x; a0.y += u.y; a0.z += u.z; a0.w += u.w;
            a1.x += v2.x; a1.y += v2.y; a1.z += v2.z; a1.w += v2.w;
        }
        *(float4*)(&xsh[t0 + 4]) = a0;
        *(float4*)(&xsh[t0 + 8]) = a1;
        *(float4*)(xp + t0 + 4) = a0;
        *(float4*)(xp + t0 + 8) = a1;
        if (tid < 4) {
            xsh[tid] = 0.0f; xsh[4100 + tid] = 0.0f;
            xp[tid] = 0.0f;  xp[4100 + tid] = 0.0f;
        }
    }
    __syncthreads();

    // Phase 2: mean_t selu(conv). lane = o (broadcast LDS reads), wave = t-chunk.
    int wave = tid >> 6;
    int lane = tid & 63;                   // = o
    float w0 = cw[lane * 5 + 0], w1 = cw[lane * 5 + 1], w2 = cw[lane * 5 + 2];
    float w3 = cw[lane * 5 + 3], w4 = cw[lane * 5 + 4];
    float bv = cb[lane];
    int c0 = wave * 512;
    float a0 = xsh[c0 + 2], a1 = xsh[c0 + 3], a2 = xsh[c0 + 4], a3 = xsh[c0 + 5];
    float acc = 0.0f;
    #pragma unroll 8
    for (int t = c0; t < c0 + 512; ++t) {
        float a4 = xsh[t + 6];
        float cv = bv + w0 * a0 + w1 * a1 + w2 * a2 + w3 * a3 + w4 * a4;
        acc += selu_f(cv);
        a0 = a1; a1 = a2; a2 = a3; a3 = a4;
    }
    __shared__ float part[8][64];
    part[wave][lane] = acc;
    __syncthreads();
    if (tid < 64) {
        float tot = 0.0f;
        #pragma unroll
        for (int w = 0; w < 8; ++w) tot += part[w][tid];
        s_out[row * 64 + tid] = tot * (1.0f / (float)T);
    }
}

// K23: SE MLP -> gate -> compressed -> af/at -> softmax sm.
// grid = B (=32), block = 512: wave = v, lane = o.
__global__ __launch_bounds__(512) void k_se_sm(
        const float* __restrict__ s_in, const float* __restrict__ w1,
        const float* __restrict__ b1, const float* __restrict__ w2,
        const float* __restrict__ b2, const float* __restrict__ awv,
        float* __restrict__ sm) {
    int b = blockIdx.x;
    int tid = threadIdx.x;
    int v = tid >> 6;
    int o = tid & 63;
    __shared__ float ssh[8][64];
    __shared__ float hsh[8][16];
    __shared__ float afs[8], ats[8];
    float so = s_in[(v * B + b) * 64 + o];
    ssh[v][o] = so;
    __syncthreads();
    if (o < 16) {
        float hv = b1[v * 16 + o];
        #pragma unroll
        for (int j = 0; j < 64; ++j) hv += ssh[v][j] * w1[(v * 16 + o) * 64 + j];
        hsh[v][o] = fmaxf(hv, 0.0f);
    }
    __syncthreads();
    float gv = b2[v * 64 + o];
    #pragma unroll
    for (int j = 0; j < 16; ++j) gv += hsh[v][j] * w2[(v * 64 + o) * 16 + j];
    float gate = 1.0f / (1.0f + __expf(-gv));
    float comp = so * gate;
    float pf = comp * awv[o];
    float pt = comp * awv[64 + o];
    #pragma unroll
    for (int m = 32; m >= 1; m >>= 1) {
        pf += __shfl_xor(pf, m, 64);
        pt += __shfl_xor(pt, m, 64);
    }
    if (o == 0) { afs[v] = pf; ats[v] = pt; }
    __syncthreads();
    if (tid < 64) {
        int f = tid >> 3, g = tid & 7;
        float a = selu_f(afs[f] + ats[g]);
        float m = a;
        m = fmaxf(m, __shfl_xor(m, 8, 64));
        m = fmaxf(m, __shfl_xor(m, 16, 64));
        m = fmaxf(m, __shfl_xor(m, 32, 64));
        float e = __expf(a - m);
        float ssum = e;
        ssum += __shfl_xor(ssum, 8, 64);
        ssum += __shfl_xor(ssum, 16, 64);
        ssum += __shfl_xor(ssum, 32, 64);
        sm[b * 64 + tid] = e / ssum;       // layout [b][f*8+g]
    }
}

// K4: out[g,b,o,t] = sum_f sm[f,g,b]*selu(conv[f,b,o,t]), conv recomputed.
// grid = B * 4 tiles * 4 og = 512 blocks, block=256. Thread owns (b, 4 t's), 16 o's.
__global__ __launch_bounds__(256) void k_out(
        const float* __restrict__ ws, const float* __restrict__ cw,
        const float* __restrict__ cb, float* __restrict__ out) {
    int blk = blockIdx.x;
    int b = blk >> 4;                      // 0..31
    int r = blk & 15;
    int tile = r >> 2;                     // 0..3
    int og = r & 3;                        // 0..3
    int t0 = tile * 1024 + threadIdx.x * 4;

    // softmax weights: block-uniform -> SGPRs
    const float* smp = ws + SM_OFF + b * 64;
    float smv[64];
    #pragma unroll
    for (int i = 0; i < 64; ++i) smv[i] = sload(smp + i);

    // xs windows: xw[f][k] = xs_pad[t0+2+k], k=0..7 (covers 4 outputs, K=5)
    float xw[8][8];
    #pragma unroll
    for (int f = 0; f < 8; ++f) {
        const float* xp = ws + XS_OFF + (size_t)(f * B + b) * XSTRIDE + t0;
        float4 q0 = *(const float4*)(xp);
        float4 q1 = *(const float4*)(xp + 4);
        float4 q2 = *(const float4*)(xp + 8);
        xw[f][0] = q0.z; xw[f][1] = q0.w;
        xw[f][2] = q1.x; xw[f][3] = q1.y; xw[f][4] = q1.z; xw[f][5] = q1.w;
        xw[f][6] = q2.x; xw[f][7] = q2.y;
    }

    #pragma unroll 1
    for (int oi = 0; oi < 16; ++oi) {
        int o = og * 16 + oi;
        float w0 = sload(cw + o * 5 + 0), w1 = sload(cw + o * 5 + 1);
        float w2 = sload(cw + o * 5 + 2), w3 = sload(cw + o * 5 + 3);
        float w4 = sload(cw + o * 5 + 4);
        float bv = sload(cb + o);
        float acc[8][4];
        #pragma unroll
        for (int g = 0; g < 8; ++g)
            #pragma unroll
            for (int dt = 0; dt < 4; ++dt) acc[g][dt] = 0.0f;
        #pragma unroll
        for (int f = 0; f < 8; ++f) {
            float cv[4];
            #pragma unroll
            for (int dt = 0; dt < 4; ++dt) {
                float c = bv + w0 * xw[f][dt] + w1 * xw[f][dt + 1] + w2 * xw[f][dt + 2]
                             + w3 * xw[f][dt + 3] + w4 * xw[f][dt + 4];
                cv[dt] = selu_f(c);
            }
            #pragma unroll
            for (int g = 0; g < 8; ++g) {
                float s = smv[f * 8 + g];
                #pragma unroll
                for (int dt = 0; dt < 4; ++dt) acc[g][dt] += s * cv[dt];
            }
        }
        #pragma unroll
        for (int g = 0; g < 8; ++g) {
            float4 o4 = make_float4(acc[g][0], acc[g][1], acc[g][2], acc[g][3]);
            *(float4*)(out + ((size_t)(g * B + b) * O + o) * T + t0) = o4;
        }
    }
}

extern "C" void kernel_launch(void* const* d_in, const int* in_sizes, int n_in,
                              void* d_out, int out_size, void* d_ws, size_t ws_size,
                              hipStream_t stream) {
    const float* x      = (const float*)d_in[0];
    const float* conv_w = (const float*)d_in[1];
    const float* conv_b = (const float*)d_in[2];
    const float* se_w1  = (const float*)d_in[3];
    const float* se_b1  = (const float*)d_in[4];
    const float* se_w2  = (const float*)d_in[5];
    const float* se_b2  = (const float*)d_in[6];
    const float* attn_w = (const float*)d_in[7];
    float* out = (float*)d_out;
    float* ws  = (float*)d_ws;

    k_xs_mean<<<V * B, 512, 0, stream>>>(x, conv_w, conv_b, ws, ws + S_OFF);
    k_se_sm<<<B, 512, 0, stream>>>(ws + S_OFF, se_w1, se_b1, se_w2, se_b2, attn_w,
                                   ws + SM_OFF);
    k_out<<<B * 4 * 4, 256, 0, stream>>>(ws, conv_w, conv_b, out);
}